// Round 8
// baseline (140.152 us; speedup 1.0000x reference)
//
#include <hip/hip_runtime.h>
#include <math.h>

typedef unsigned short ushort_t;
typedef __attribute__((ext_vector_type(8))) __bf16 bf16x8;
typedef __attribute__((ext_vector_type(4))) float floatx4;

#define B_    256
#define I_    1152
#define J_    10
#define DIN_  8
#define DOUT_ 16
#define K_    (I_*DIN_)     // 9216
#define N_    (J_*DOUT_)    // 160
#define KSPLIT 16           // total split-K per output tile
#define KCHUNK (K_/KSPLIT)  // 576 (72 i's per wave)
#define KSTEPS (KCHUNK/32)  // 18

// Packed-chunk stride: one (mb|nt, kc) chunk = 18 steps * 2 planes * 1KB
// = 36,864 B; pad +1KB -> 37 KB (odd multiple of 1KB) so concurrent
// streams land on different L2 channel phases. Unit below = 16 B.
#define CHUNK16 2368        // 37*1024/16

static __device__ __forceinline__ ushort_t f2bf(float f) {
    unsigned int u = __float_as_uint(f);
    u += 0x7fffu + ((u >> 16) & 1u);     // RNE
    return (ushort_t)(u >> 16);
}
static __device__ __forceinline__ float bf2f(ushort_t h) {
    return __uint_as_float(((unsigned int)h) << 16);
}

// ---------------------------------------------------------------------------
// prep_xpack (once): x -> fragment-major Dekker bf16 hi/lo planes (r7, passed).
// Layout (16B units): (mb*16+kc)*CHUNK16 + s*128 + p*64 + q*16 + r.
// ---------------------------------------------------------------------------
__global__ __launch_bounds__(256)
void prep_xpack_kernel(const float* __restrict__ x, ushort_t* __restrict__ xPk)
{
    const int gid = blockIdx.x * 256 + threadIdx.x;   // 0..294911
    const int f   = gid * 8;
    const int row = f / K_;                 // b: 0..255
    const int kk  = f - row * K_;
    const int kc  = kk / KCHUNK;            // 0..15
    const int t   = kk - kc * KCHUNK;
    const int s   = t >> 5;                 // 0..17
    const int q   = (t & 31) >> 3;          // 0..3
    const int mb  = row >> 4, r = row & 15;

    const float* src = x + (size_t)f;
    bf16x8 h8, l8;
    #pragma unroll
    for (int e = 0; e < 8; ++e) {
        float v = src[e];
        __bf16 h = (__bf16)v;
        h8[e] = h;
        l8[e] = (__bf16)(v - (float)h);
    }
    bf16x8* dst = (bf16x8*)xPk + (size_t)(mb * 16 + kc) * CHUNK16 + s * 128 + q * 16 + r;
    dst[0]  = h8;       // plane 0 (hi)
    dst[64] = l8;       // plane 1 (lo)
}

// ---------------------------------------------------------------------------
// prep_wpack (once): W -> fragment-major fp32 (exact copy, permuted; r7).
// Layout (float4 units): (nt*16+kc)*CHUNK16 + (s*2+p)*64 + q*16 + r.
// ---------------------------------------------------------------------------
__global__ __launch_bounds__(256)
void prep_wpack_kernel(const float* __restrict__ W, float* __restrict__ wPk)
{
    const int gid = blockIdx.x * 256 + threadIdx.x;   // 0..368639
    const int f   = gid * 4;
    const int i   = f / 1280;               // 0..1151
    const int rem = f - i * 1280;
    const int no  = rem >> 3;               // nt*16 + r
    const int p   = (rem >> 2) & 1;
    const int nt  = no >> 4, r = no & 15;
    const int kc  = i / 72;
    const int m   = i - kc * 72;
    const int s   = m >> 2, q = m & 3;

    float4 v = *(const float4*)(W + (size_t)f);
    ((float4*)wPk)[(size_t)(nt * 16 + kc) * CHUNK16 + (s * 2 + p) * 64 + q * 16 + r] = v;
}

// ---------------------------------------------------------------------------
// Round-23 s-GEMM: r7's packed-operand kernel with ONE change: 2x2 register
// tiling. Each block computes (mb0,mb1)x(nt0,nt1): x-loads shared across the
// two nt, W-loads shared across the two mb -> total operand line-traffic
// halves (190->95 MB/dispatch; misses 2.3M->1.15M). Grid 1280->320 blocks
// (kb=blk&7 kept); prefetch ring deepened to 3 (24 outstanding loads/wave
// compensates the lower TLP). Per-tile MFMA chains + reduction order are
// IDENTICAL to r7 -> bit-identical output.
// ---------------------------------------------------------------------------
__global__ __launch_bounds__(128)
void gemm_s_part_kernel(const ushort_t* __restrict__ xPk, const float* __restrict__ wPk,
                        const float* __restrict__ blog,
                        float* __restrict__ pbuf, const int iter)
{
    const int tid  = threadIdx.x;          // 0..127
    const int blk  = blockIdx.x;           // 0..319
    const int kb   = blk & 7;              // K-slice / XCD (perf-only heuristic)
    const int grp  = blk >> 3;             // 0..39
    const int mbp  = grp / 5;              // 0..7
    const int ntp  = grp - mbp * 5;        // 0..4
    const int mb0  = mbp * 2, mb1 = mbp * 2 + 1;
    const int nt0  = ntp,     nt1 = ntp + 5;
    const int lane = tid & 63;
    const int w    = tid >> 6;             // 0..1
    const int kc   = kb * 2 + w;           // 0..15: wave's k-chunk index

    __shared__ float   c2_lds[144 * 2];    // c[i][nt0], c[i][nt1]
    __shared__ floatx4 part[8 * 64];       // [w][t4][lane]

    if (iter > 0) {
        for (int r2 = tid; r2 < 144; r2 += 128) {
            const float* br = blog + (size_t)(kb * 144 + r2) * J_;
            float bv[J_];
            float mx = -1e30f;
            #pragma unroll
            for (int j = 0; j < J_; ++j) { bv[j] = br[j]; mx = fmaxf(mx, bv[j]); }
            float sum = 0.f;
            #pragma unroll
            for (int j = 0; j < J_; ++j) { bv[j] = __expf(bv[j] - mx); sum += bv[j]; }
            c2_lds[r2 * 2]     = bv[nt0] / sum;
            c2_lds[r2 * 2 + 1] = bv[nt1] / sum;
        }
        __syncthreads();
    }

    {
        const int q = lane >> 4;
        const bf16x8* xp0 = (const bf16x8*)xPk + (size_t)(mb0 * 16 + kc) * CHUNK16 + lane;
        const bf16x8* xp1 = (const bf16x8*)xPk + (size_t)(mb1 * 16 + kc) * CHUNK16 + lane;
        const float4* wq0 = (const float4*)wPk + (size_t)(nt0 * 16 + kc) * CHUNK16 + lane;
        const float4* wq1 = (const float4*)wPk + (size_t)(nt1 * 16 + kc) * CHUNK16 + lane;
        floatx4 a00 = {0.f,0.f,0.f,0.f}, a10 = a00, a01 = a00, a11 = a00;

        // 3-deep prefetch ring (fully unrolled loop -> static indices)
        bf16x8 rh0[3], rl0[3], rh1[3], rl1[3];
        float4 rw00[3], rw01[3], rw10[3], rw11[3];
        #pragma unroll
        for (int s = 0; s < 3; ++s) {
            rh0[s]  = xp0[s * 128];  rl0[s]  = xp0[s * 128 + 64];
            rh1[s]  = xp1[s * 128];  rl1[s]  = xp1[s * 128 + 64];
            rw00[s] = wq0[s * 128];  rw01[s] = wq0[s * 128 + 64];
            rw10[s] = wq1[s * 128];  rw11[s] = wq1[s * 128 + 64];
        }
        #pragma unroll
        for (int s = 0; s < KSTEPS; ++s) {
            const int sl = s % 3;
            bf16x8 ah0 = rh0[sl], al0 = rl0[sl], ah1 = rh1[sl], al1 = rl1[sl];
            float4 w00 = rw00[sl], w01 = rw01[sl], w10 = rw10[sl], w11 = rw11[sl];
            if (s + 3 < KSTEPS) {
                rh0[sl]  = xp0[(s + 3) * 128];  rl0[sl]  = xp0[(s + 3) * 128 + 64];
                rh1[sl]  = xp1[(s + 3) * 128];  rl1[sl]  = xp1[(s + 3) * 128 + 64];
                rw00[sl] = wq0[(s + 3) * 128];  rw01[sl] = wq0[(s + 3) * 128 + 64];
                rw10[sl] = wq1[(s + 3) * 128];  rw11[sl] = wq1[(s + 3) * 128 + 64];
            }
            float cs0, cs1;
            if (iter == 0) { cs0 = 0.1f; cs1 = 0.1f; }
            else {
                const int ii = (w * 72 + 4 * s + q) * 2;
                cs0 = c2_lds[ii];
                cs1 = c2_lds[ii + 1];
            }
            float wv0[8] = {w00.x, w00.y, w00.z, w00.w, w01.x, w01.y, w01.z, w01.w};
            float wv1[8] = {w10.x, w10.y, w10.z, w10.w, w11.x, w11.y, w11.z, w11.w};
            bf16x8 bh0, bl0, bh1, bl1;
            #pragma unroll
            for (int e = 0; e < 8; ++e) {
                float p0 = wv0[e] * cs0;
                __bf16 g0 = (__bf16)p0;
                bh0[e] = g0;
                bl0[e] = (__bf16)(p0 - (float)g0);
                float p1 = wv1[e] * cs1;
                __bf16 g1 = (__bf16)p1;
                bh1[e] = g1;
                bl1[e] = (__bf16)(p1 - (float)g1);
            }
            a00 = __builtin_amdgcn_mfma_f32_16x16x32_bf16(ah0, bh0, a00, 0, 0, 0);
            a00 = __builtin_amdgcn_mfma_f32_16x16x32_bf16(al0, bh0, a00, 0, 0, 0);
            a00 = __builtin_amdgcn_mfma_f32_16x16x32_bf16(ah0, bl0, a00, 0, 0, 0);
            a10 = __builtin_amdgcn_mfma_f32_16x16x32_bf16(ah1, bh0, a10, 0, 0, 0);
            a10 = __builtin_amdgcn_mfma_f32_16x16x32_bf16(al1, bh0, a10, 0, 0, 0);
            a10 = __builtin_amdgcn_mfma_f32_16x16x32_bf16(ah1, bl0, a10, 0, 0, 0);
            a01 = __builtin_amdgcn_mfma_f32_16x16x32_bf16(ah0, bh1, a01, 0, 0, 0);
            a01 = __builtin_amdgcn_mfma_f32_16x16x32_bf16(al0, bh1, a01, 0, 0, 0);
            a01 = __builtin_amdgcn_mfma_f32_16x16x32_bf16(ah0, bl1, a01, 0, 0, 0);
            a11 = __builtin_amdgcn_mfma_f32_16x16x32_bf16(ah1, bh1, a11, 0, 0, 0);
            a11 = __builtin_amdgcn_mfma_f32_16x16x32_bf16(al1, bh1, a11, 0, 0, 0);
            a11 = __builtin_amdgcn_mfma_f32_16x16x32_bf16(ah1, bl1, a11, 0, 0, 0);
        }
        // t4: 0=(mb0,nt0) 1=(mb1,nt0) 2=(mb0,nt1) 3=(mb1,nt1)
        part[(w * 4 + 0) * 64 + lane] = a00;
        part[(w * 4 + 1) * 64 + lane] = a10;
        part[(w * 4 + 2) * 64 + lane] = a01;
        part[(w * 4 + 3) * 64 + lane] = a11;
    }
    __syncthreads();

    // ---- in-block pair-reduce -> plain store of four 16x16 partials ----
    const int row  = tid >> 3;             // 0..15 (b_local)
    const int col2 = (tid & 7) * 2;        // o pair base
    #pragma unroll
    for (int t4 = 0; t4 < 4; ++t4) {
        const int mb = (t4 & 1) ? mb1 : mb0;
        const int nt = (t4 >> 1) ? nt1 : nt0;
        float2 v2;
        #pragma unroll
        for (int h = 0; h < 2; ++h) {
            const int o      = col2 + h;
            const int lane_c = ((row >> 2) << 4) | o;   // C/D: col=lane&15, row=quad*4+reg
            const int reg    = row & 3;
            ((float*)&v2)[h] = part[(0 * 4 + t4) * 64 + lane_c][reg]
                             + part[(1 * 4 + t4) * 64 + lane_c][reg];
        }
        *(float2*)(pbuf + ((size_t)(nt * 16 + mb) * 8 + kb) * 256 + row * 16 + col2) = v2;
    }
}

// ---------------------------------------------------------------------------
// Stage 2: reduce 8 k-slice partials per tile + squash + emit (unchanged r5).
// ---------------------------------------------------------------------------
__global__ __launch_bounds__(256)
void reduce_squash_kernel(const float* __restrict__ pbuf, float* __restrict__ s_out,
                          ushort_t* __restrict__ Sbt_hi, ushort_t* __restrict__ Sbt_lo,
                          const int iter)
{
    const int tile = blockIdx.x;           // 0..159 (tile = nt*16+mb)
    const int mb   = tile & 15;
    const int nt   = tile >> 4;
    const int t    = threadIdx.x;          // 0..255
    const int row  = t >> 4;               // 0..15 (b_local)
    const int o    = t & 15;               // 0..15

    const float* pb = pbuf + (size_t)tile * 8 * 256 + row * 16 + o;
    float v = 0.f;
    #pragma unroll
    for (int u = 0; u < 8; ++u)
        v += pb[u * 256];

    float sq = v * v;
    #pragma unroll
    for (int off = 1; off < 16; off <<= 1)  // 16 consecutive lanes = one b row
        sq += __shfl_xor(sq, off, 16);
    float l2 = sqrtf(sq);
    float val = v * (l2 / (1.f + sq));
    const int b  = mb * 16 + row;
    const int jo = nt * 16 + o;
    if (iter == 2) {
        s_out[(size_t)b * N_ + jo] = val;
    } else {
        ushort_t hi = f2bf(val);
        Sbt_hi[(size_t)jo * B_ + b] = hi;
        Sbt_lo[(size_t)jo * B_ + b] = f2bf(val - bf2f(hi));
    }
}

// ---------------------------------------------------------------------------
// b-update GEMM (unchanged r5 — reads original x/W; its access patterns are
// dense/channel-spread: x along k in full 64B lines, Sbt contiguous).
// ---------------------------------------------------------------------------
__global__ __launch_bounds__(256)
void gemm_bupd_kernel(const float* __restrict__ x,
                      const ushort_t* __restrict__ Sbt_hi, const ushort_t* __restrict__ Sbt_lo,
                      const float* __restrict__ W, float* __restrict__ blog,
                      const int first)
{
    // bijective remap: XCD (blk&7) gets wv in [xcd*360, xcd*360+360) -> mt
    // in [xcd*72, xcd*72+72) contiguous (720 blocks, 720%8==0).
    int wv   = (blockIdx.x & 7) * 360 + (blockIdx.x >> 3) * 4 + (threadIdx.x >> 6);
    int lane = threadIdx.x & 63;
    int mt = wv / 5;                                  // 0..575
    int jp = wv - mt * 5;                             // j-pair: j0=2jp, j1=2jp+1
    int j0 = jp * 2, j1 = jp * 2 + 1;
    int r = lane & 15, q = lane >> 4;
    const float* xp = x + (size_t)(8 * q) * K_ + (mt * 16 + r);   // + (s*32+e)*K_
    size_t b0off = (size_t)(j0 * 16 + r) * B_ + 8 * q;
    size_t b1off = (size_t)(j1 * 16 + r) * B_ + 8 * q;
    floatx4 acc0 = {0.f, 0.f, 0.f, 0.f};
    floatx4 acc1 = {0.f, 0.f, 0.f, 0.f};

    float xcur[8], xnxt[8];
    #pragma unroll
    for (int e = 0; e < 8; ++e) xcur[e] = xp[(size_t)e * K_];
    #pragma unroll
    for (int s = 0; s < B_ / 32; ++s) {
        if (s + 1 < B_ / 32) {               // prefetch next step's x column slice
            #pragma unroll
            for (int e = 0; e < 8; ++e)
                xnxt[e] = xp[(size_t)((s + 1) * 32 + e) * K_];
        }
        bf16x8 ah, al;
        #pragma unroll
        for (int e = 0; e < 8; ++e) {
            float v = xcur[e];
            __bf16 h = (__bf16)v;
            ah[e] = h;
            al[e] = (__bf16)(v - (float)h);
        }
        bf16x8 bh0 = *(const bf16x8*)(Sbt_hi + b0off + s * 32);
        bf16x8 bl0 = *(const bf16x8*)(Sbt_lo + b0off + s * 32);
        bf16x8 bh1 = *(const bf16x8*)(Sbt_hi + b1off + s * 32);
        bf16x8 bl1 = *(const bf16x8*)(Sbt_lo + b1off + s * 32);
        acc0 = __builtin_amdgcn_mfma_f32_16x16x32_bf16(ah, bh0, acc0, 0, 0, 0);
        acc0 = __builtin_amdgcn_mfma_f32_16x16x32_bf16(al, bh0, acc0, 0, 0, 0);
        acc0 = __builtin_amdgcn_mfma_f32_16x16x32_bf16(ah, bl0, acc0, 0, 0, 0);
        acc1 = __builtin_amdgcn_mfma_f32_16x16x32_bf16(ah, bh1, acc1, 0, 0, 0);
        acc1 = __builtin_amdgcn_mfma_f32_16x16x32_bf16(al, bh1, acc1, 0, 0, 0);
        acc1 = __builtin_amdgcn_mfma_f32_16x16x32_bf16(ah, bl1, acc1, 0, 0, 0);
        #pragma unroll
        for (int e = 0; e < 8; ++e) xcur[e] = xnxt[e];
    }
    // rows q*4+reg -> i = mt*2 + (q>>1), d = (q&1)*4 + reg; col -> o = lane&15
    int i  = mt * 2 + (q >> 1);
    int d0 = (q & 1) * 4;
    int o  = lane & 15;
    int iw = mt * 2 + (lane >> 5);
    {
        const float4 w4 = *(const float4*)(W + ((((size_t)i * J_ + j0) * DOUT_ + o) * DIN_ + d0));
        float val = acc0[0] * w4.x + acc0[1] * w4.y + acc0[2] * w4.z + acc0[3] * w4.w;
        #pragma unroll
        for (int off = 1; off < 32; off <<= 1)
            val += __shfl_xor(val, off, 32);
        if ((lane & 31) == 0) {
            float* dst = blog + (size_t)iw * J_ + j0;
            if (first) *dst = val; else *dst += val;
        }
    }
    {
        const float4 w4 = *(const float4*)(W + ((((size_t)i * J_ + j1) * DOUT_ + o) * DIN_ + d0));
        float val = acc1[0] * w4.x + acc1[1] * w4.y + acc1[2] * w4.z + acc1[3] * w4.w;
        #pragma unroll
        for (int off = 1; off < 32; off <<= 1)
            val += __shfl_xor(val, off, 32);
        if ((lane & 31) == 0) {
            float* dst = blog + (size_t)iw * J_ + j1;
            if (first) *dst = val; else *dst += val;
        }
    }
}

// ---------------------------------------------------------------------------
extern "C" void kernel_launch(void* const* d_in, const int* in_sizes, int n_in,
                              void* d_out, int out_size, void* d_ws, size_t ws_size,
                              hipStream_t stream)
{
    const float* x = (const float*)d_in[0];   // [B, I, DIN]
    const float* W = (const float*)d_in[1];   // [I, J, DOUT, DIN]
    float* s_out = (float*)d_out;             // [B, J, DOUT]

    char* ws = (char*)d_ws;
    ushort_t* Sbt_hi = (ushort_t*)(ws);                 //    81,920 B
    ushort_t* Sbt_lo = (ushort_t*)(ws + 81920);         //    81,920 B
    float*    blog   = (float*)   (ws + 163840);        //    46,080 B
    float*    pbuf   = (float*)   (ws + 262144);        // 1,310,720 B
    ushort_t* xPk    = (ushort_t*)(ws + 1572864);       // 9,699,328 B (256 chunks * 37KB)
    float*    wPk    = (float*)   (ws + 11272192);      // 6,062,080 B (160 chunks * 37KB)
                                                        // total ~17.3 MB

    prep_xpack_kernel<<<1152, 256, 0, stream>>>(x, xPk);
    prep_wpack_kernel<<<1440, 256, 0, stream>>>(W, wPk);

    for (int it = 0; it < 3; ++it) {
        gemm_s_part_kernel<<<320, 128, 0, stream>>>(xPk, wPk, blog, pbuf, it);
        reduce_squash_kernel<<<160, 256, 0, stream>>>(pbuf, s_out,
                                                      Sbt_hi, Sbt_lo, it);
        if (it < 2)
            gemm_bupd_kernel<<<720, 256, 0, stream>>>(x, Sbt_hi, Sbt_lo,
                                                      W, blog, it == 0 ? 1 : 0);
    }
}